// Round 1
// 244.367 us; speedup vs baseline: 1.0054x; 1.0054x over previous
//
#include <hip/hip_runtime.h>

#define BATCH 64
#define M_GT  100
#define M1    101
#define NANCH 8732
#define BLOCK 256
#define NPT   2                    // anchors per thread -> dwordx2 stores
#define NTILE (BLOCK * NPT)        // 512
#define NX    18                   // ceil(8732/512)
#define NBLK  (NX * BATCH)         // 1152 blocks = 4608 waves = 4.5/SIMD
#define GROUP 8                    // rows per store burst -> 8 outstanding stores/wave
#define MBULK ((M1 / GROUP) * GROUP)   // 96
#define MTAIL (M1 - MBULK)             // 5

// Single fused dispatch. Each block builds the 101-row GT table in LDS
// (redundant across blocks but L2-served, ~1 µs total). Masking: pad row
// (m=0) and invalid rows (cls==0) get area=+inf -> iou = inter*rcp(inf) = +0
// exactly, never NaN.
//
// R(this): store-depth restructure. Previous version kept ~1 outstanding
// 1KB store per wave (compiler vmcnt before reusing the single iou quad),
// giving ~2.3MB chip-wide in flight vs the ~6-7MB latency-BW product ->
// 2.3 TB/s write BW. Now: groups of 8 rows on 8 distinct register pairs
// (depth-8 store window) and 2x the waves (NPT 4->2, 1152 blocks).
__global__ __launch_bounds__(BLOCK) void encode_fused(
    const float* __restrict__ labels,   // [B, M, 5]
    const float* __restrict__ dboxes,   // [N, 4]
    float* __restrict__ out_labeled,    // [B, N, 5]
    float* __restrict__ out_ious)       // [B, M1, N]
{
    __shared__ float4 s_box[M1];        // {x1,y1,x2,y2}
    __shared__ float  s_ar[M1], s_cls[M1];

    const int tid = threadIdx.x;
    const int b   = blockIdx.x / NX;
    const int nb  = blockIdx.x % NX;

    if (tid < M1) {
        float x1 = 0.f, y1 = 0.f, x2 = 0.f, y2 = 0.f, cls = 0.f;
        float ar = __builtin_inff();
        if (tid >= 1) {
            const float* row = labels + ((size_t)b * M_GT + (tid - 1)) * 5;
            x1 = row[0]; y1 = row[1]; x2 = row[2]; y2 = row[3]; cls = row[4];
            if (cls != 0.0f) ar = (x2 - x1) * (y2 - y1);
        }
        s_box[tid] = make_float4(x1, y1, x2, y2);
        s_ar[tid] = ar; s_cls[tid] = cls;
    }
    __syncthreads();

    const int n0 = nb * NTILE + tid * NPT;
    if (n0 >= NANCH) return;           // NANCH % 2 == 0 -> whole pair in/out

    float ax1[NPT], ay1[NPT], ax2[NPT], ay2[NPT], aa[NPT];
    #pragma unroll
    for (int i = 0; i < NPT; ++i) {
        const float4 d = *reinterpret_cast<const float4*>(dboxes + (size_t)(n0 + i) * 4);
        ax1[i] = d.x; ay1[i] = d.y; ax2[i] = d.z; ay2[i] = d.w;
        aa[i]  = (d.z - d.x) * (d.w - d.y);
    }

    float* const irow = out_ious + (size_t)b * M1 * NANCH + n0;

    // best=-1: pad rows give iou=+0; strict > = numpy first-occurrence argmax.
    float best[NPT]; int besti[NPT];
    #pragma unroll
    for (int i = 0; i < NPT; ++i) { best[i] = -1.0f; besti[i] = 0; }

    // One row: compute NPT ious, update running argmax, store 8B.
    // Called only from fully-unrolled loops -> all indexing static.
    auto row_body = [&](int m) {
        const float4 g = s_box[m];      // ds_read_b128 broadcast
        const float ga = s_ar[m];       // ds_read_b32 broadcast
        float iou[NPT];
        #pragma unroll
        for (int i = 0; i < NPT; ++i) {
            const float ix1 = fmaxf(g.x, ax1[i]), iy1 = fmaxf(g.y, ay1[i]);
            const float ix2 = fminf(g.z, ax2[i]), iy2 = fminf(g.w, ay2[i]);
            const float iw = fmaxf(ix2 - ix1, 0.0f), ih = fmaxf(iy2 - iy1, 0.0f);
            const float inter = iw * ih;
            iou[i] = inter * __builtin_amdgcn_rcpf(ga + aa[i] - inter);  // validated R3/R7
            if (iou[i] > best[i]) { best[i] = iou[i]; besti[i] = m; }
        }
        float2 w; w.x = iou[0]; w.y = iou[1];
        *reinterpret_cast<float2*>(irow + (size_t)m * NANCH) = w;   // 512B per wave-instr
    };

    // Bulk: 12 groups of 8 rows. The 8 stores of a group sit on 8 distinct
    // register pairs -> up to 8 outstanding stores per wave before any
    // vmcnt reuse-wait; next group's VALU overlaps the in-flight stores.
    for (int mg = 0; mg < MBULK; mg += GROUP) {
        #pragma unroll
        for (int r = 0; r < GROUP; ++r) row_body(mg + r);
    }
    // Tail: 5 rows.
    #pragma unroll
    for (int r = 0; r < MTAIL; ++r) row_body(MBULK + r);

    // Epilogue
    float lw[NPT * 5];
    #pragma unroll
    for (int i = 0; i < NPT; ++i) {
        const int idx = (best[i] > 0.5f) ? besti[i] : 0;
        float ox = 0.f, oy = 0.f, ow = 0.f, oh = 0.f, pcls = 0.f;
        if (idx != 0) {   // iou>0.5 winner is always a valid (cls!=0) row
            const float4 t = s_box[idx];
            const float aw = ax2[i] - ax1[i], ah = ay2[i] - ay1[i];
            ox = (0.5f * (t.x + t.z) - 0.5f * (ax1[i] + ax2[i])) / aw;
            oy = (0.5f * (t.y + t.w) - 0.5f * (ay1[i] + ay2[i])) / ah;
            ow = __logf((t.z - t.x) / aw);
            oh = __logf((t.w - t.y) / ah);
            pcls = s_cls[idx];
        }
        lw[i * 5 + 0] = ox; lw[i * 5 + 1] = oy; lw[i * 5 + 2] = ow;
        lw[i * 5 + 3] = oh; lw[i * 5 + 4] = pcls;
    }
    // 10 contiguous floats = 40B, 8B-aligned (n0 even) -> 5 dwordx2 stores
    float* lrow = out_labeled + ((size_t)b * NANCH + n0) * 5;
    #pragma unroll
    for (int k = 0; k < 5; ++k) {
        float2 v; v.x = lw[k * 2]; v.y = lw[k * 2 + 1];
        *reinterpret_cast<float2*>(lrow + k * 2) = v;
    }
}

extern "C" void kernel_launch(void* const* d_in, const int* in_sizes, int n_in,
                              void* d_out, int out_size, void* d_ws, size_t ws_size,
                              hipStream_t stream) {
    const float* labels = (const float*)d_in[0];
    const float* dboxes = (const float*)d_in[1];
    float* out_labeled = (float*)d_out;
    float* out_ious    = out_labeled + (size_t)BATCH * NANCH * 5;

    encode_fused<<<dim3(NBLK), dim3(BLOCK), 0, stream>>>(labels, dboxes, out_labeled, out_ious);
}